// Round 11
// baseline (142.551 us; speedup 1.0000x reference)
//
#include <hip/hip_runtime.h>
#include <cstdio>
#include <cstdint>

static constexpr int  MPIX   = 51529;   // 227*227
static constexpr int  NBATCH = 8;
static constexpr int  NTH    = 256;     // number of thresholds
static constexpr int  HD     = 257;     // rank histogram dim (0..256)
static constexpr int  HP     = 260;     // padded H pitch (rows 16B-aligned)
static constexpr int  GW     = 3;       // rank-group width
static constexpr int  GRP    = 86;      // ceil(257/3); 86*8 = 688 phase2 blocks
static constexpr int  NCHB   = 51;      // bin chunks of 1024 pixels
static constexpr int  CAPG   = 4096;    // records per (batch,group); post-filter mean ~420

// ws layout (float slots) — d_ws is 256 MiB
static constexpr long PSA_OFF   = 0;     // 256 floats (sorted phi_a)
static constexpr long IA_OFF    = 256;   // 256 ints
static constexpr long PSB_OFF   = 512;   // 256 floats
static constexpr long IB_OFF    = 768;   // 256 ints
static constexpr long MVC_OFF   = 1024;  // 1 int (matvec ctr; zeroed by k_sortpub)
static constexpr long BASEA_OFF = 1056;  // 257 ints (LUT: first idx with psa[i] >= j)
static constexpr long BASEB_OFF = 1344;  // 257 ints
static constexpr long GCUR_OFF  = 1664;  // 688 ints (per-(b,g) record cursors; zeroed by sortpub)
static constexpr long H_OFF     = 2560;
static constexpr long H_SZ      = (long)NBATCH * HD * HP;            // 534560
static constexpr long GBC_OFF   = H_OFF + H_SZ;                      // 537120
static constexpr long GBC_SZ    = (long)NBATCH * NTH * NTH;          // 524288
static constexpr long RECAB_OFF = GBC_OFF + GBC_SZ;                  // 1061408 (even -> float2 ok)
static constexpr long RECAB_SZ  = (long)NBATCH * GRP * CAPG * 2;     // 5636096
static constexpr long RECK_OFF  = RECAB_OFF + RECAB_SZ;              // 6697504
static constexpr long RECK_SZ   = (long)NBATCH * GRP * CAPG;         // 2818048
static constexpr long PART_OFF  = RECK_OFF + RECK_SZ;                // 9515552
static constexpr long PART_SZ   = 256 * 256;                         // 65536
static constexpr long TOTAL_FLOATS = PART_OFF + PART_SZ;             // ~38.3 MB

__device__ __forceinline__ float clamp01(float v) {
    return fminf(fmaxf(v, 0.f), 1.f);
}

// LUT decode: c0 = first idx with lv[i] >= v ; c1 = first idx with lv[i] > v-1
__device__ __forceinline__ void decode_lut(const float* __restrict__ lv,
                                           const int* __restrict__ lbase,
                                           float v, int& c1, int& c0) {
    if (v <= 0.f) { c1 = 0; c0 = 0; return; }
    int j = min((int)v, 255);
    int i = lbase[j];
    while (i < 256 && lv[i] < v) ++i;
    c0 = i;
    float u = v - 1.f;
    if (u < 0.f) { c1 = 0; return; }
    int j1 = min((int)u, 255);
    int i1 = lbase[j1];
    while (i1 < 256 && lv[i1] <= u) ++i1;
    c1 = i1;
}

// one block: sort both threshold sets, publish tables+LUTs, zero cursors & mvc
__global__ void __launch_bounds__(256)
k_sortpub(const float* __restrict__ pa, const float* __restrict__ pb,
          float* __restrict__ psa, int* __restrict__ ia,
          float* __restrict__ psb, int* __restrict__ ib,
          int* __restrict__ baseA, int* __restrict__ baseB,
          int* __restrict__ gcur, int* __restrict__ mvc) {
    __shared__ float raw[256];
    __shared__ float srt[256];
    __shared__ int   sidx[256];
    int t = threadIdx.x;
    for (int i = t; i < NBATCH * GRP; i += 256) gcur[i] = 0;
    if (t == 0) *mvc = 0;
    // --- A ---
    raw[t] = pa[t];
    __syncthreads();
    {
        float v = raw[t]; int c = 0;
        for (int j = 0; j < 256; ++j) { float w = raw[j]; c += (w < v) || (w == v && j < t); }
        srt[c] = v; sidx[c] = t;
    }
    __syncthreads();
    psa[t] = srt[t]; ia[t] = sidx[t];
    {
        float q = (float)t;
        int lo = 0, hi = 256;
        while (lo < hi) { int m = (lo + hi) >> 1; if (srt[m] < q) lo = m + 1; else hi = m; }
        baseA[t] = lo;
        if (t == 0) baseA[256] = 256;
    }
    raw[t] = pb[t];     // raw no longer read (sort loop done pre-barrier)
    __syncthreads();    // baseA srt-reads done before overwriting srt below
    // --- B ---
    {
        float v = raw[t]; int c = 0;
        for (int j = 0; j < 256; ++j) { float w = raw[j]; c += (w < v) || (w == v && j < t); }
        srt[c] = v; sidx[c] = t;
    }
    __syncthreads();
    psb[t] = srt[t]; ib[t] = sidx[t];
    {
        float q = (float)t;
        int lo = 0, hi = 256;
        while (lo < hi) { int m = (lo + hi) >> 1; if (srt[m] < q) lo = m + 1; else hi = m; }
        baseB[t] = lo;
        if (t == 0) baseB[256] = 256;
    }
}

// bin: block (chunk c of 1024 px, batch b). Decodes each pixel ONCE, FILTERS useless
// records (cb1==0 && wb==0 contribute to no read output entry — ~50% of pixels),
// emits (a,bd,key) into flat per-(b,g) arrays via LDS-count + global-cursor reserve.
__global__ void __launch_bounds__(256)
k_bin(const float* __restrict__ x,
      const float* __restrict__ psa, const float* __restrict__ psb,
      const int* __restrict__ baseA, const int* __restrict__ baseB,
      int* __restrict__ gcur, float2* __restrict__ recAB, uint32_t* __restrict__ recK) {
    __shared__ float la[256], lb[256];
    __shared__ int   lbA[257], lbB[257];
    __shared__ float lx[1025];
    __shared__ int   lcnt[GRP], lbs[GRP];

    int t = threadIdx.x;
    int c = blockIdx.x, b = blockIdx.y;
    int k0 = c * 1024;

    la[t] = psa[t]; lb[t] = psb[t];
    lbA[t] = baseA[t]; lbB[t] = baseB[t];
    if (t == 0) { lbA[256] = 256; lbB[256] = 256; }
    if (t < GRP) lcnt[t] = 0;
    for (int i = t; i < 1024; i += 256) {
        int k = k0 + i;
        lx[i] = (k < MPIX) ? x[(long)b * MPIX + k] : 0.f;
    }
    if (t == 0) lx[1024] = (k0 + 1024 < MPIX) ? x[(long)b * MPIX + k0 + 1024] : 0.f;
    __syncthreads();

    float    av[4], bdv[4];
    uint32_t keyv[4];
    int      g0v[4], g1v[4];
    bool     valv[4];
#pragma unroll
    for (int p = 0; p < 4; ++p) {
        int i = p * 256 + t;
        int k = k0 + i;
        valv[p] = (k < MPIX);
        g0v[p] = 0; g1v[p] = -1;
        if (valv[p]) {
            float a  = lx[i];
            float bd = a - lx[i + 1];
            int ca1, ca0, cb1, cb0;
            decode_lut(la, lbA, a, ca1, ca0);
            decode_lut(lb, lbB, bd, cb1, cb0);
            int wa = min(ca0 - ca1, 127);
            int wb = min(cb0 - cb1, 127);
            // FILTER: H/Gb outputs only read for cb1>=1; Ga/Csp need wb>=1.
            if (cb1 == 0 && wb == 0) { valv[p] = false; continue; }
            av[p] = a; bdv[p] = bd;
            keyv[p] = (uint32_t)ca1 | ((uint32_t)wa << 9)
                    | ((uint32_t)cb1 << 16) | ((uint32_t)wb << 25);
            int g0 = ca1 / GW;
            int g1 = min(ca1 + max(wa, 1) - 1, 256) / GW;
            g0v[p] = g0; g1v[p] = g1;
            for (int g = g0; g <= g1; ++g) atomicAdd(&lcnt[g], 1);
        }
    }
    __syncthreads();
    if (t < GRP) {
        lbs[t] = atomicAdd(&gcur[b * GRP + t], lcnt[t]);
        lcnt[t] = 0;
    }
    __syncthreads();
#pragma unroll
    for (int p = 0; p < 4; ++p) {
        if (valv[p]) {
            float2 rec = make_float2(av[p], bdv[p]);
            for (int g = g0v[p]; g <= g1v[p]; ++g) {
                int slot = lbs[g] + atomicAdd(&lcnt[g], 1);
                if (slot < CAPG) {
                    long off = ((long)(b * GRP + g)) * CAPG + slot;
                    recAB[off] = rec;
                    recK[off]  = keyv[p];
                }
            }
        }
    }
}

// phase2: block (group g, batch b). Flat record loop, LDS accumulate, row scan, flush.
// IDEMPOTENT (reads only recAB/recK/gcur/tables; rewrites its own H/GbC rows).
__global__ void __launch_bounds__(256)
k_phase2(const float2* __restrict__ recAB, const uint32_t* __restrict__ recK,
         const int* __restrict__ gcur,
         const float* __restrict__ psa, const float* __restrict__ psb,
         float* __restrict__ H, float* __restrict__ GbC) {
    __shared__ float lb[256];
    __shared__ float lHG[6][257];   // rows 0..2 = H, rows 3..5 = Gb
    __shared__ float lT[6][257];
    __shared__ float lGa[256 * 3];  // [s*3 + d]
    __shared__ float lCsp[3][256];

    int t = threadIdx.x;
    int g = blockIdx.x, b = blockIdx.y;
    int r0 = g * GW;
    int rlen = min(GW, HD - r0);

    lb[t] = psb[t];
    float la0 = psa[min(r0,     255)];
    float la1 = psa[min(r0 + 1, 255)];
    float la2 = psa[min(r0 + 2, 255)];
    for (int i = t; i < 6 * 257; i += 256) (&lHG[0][0])[i] = 0.f;
    for (int i = t; i < 256 * 3; i += 256) lGa[i] = 0.f;
    for (int i = t; i < 3 * 256; i += 256) (&lCsp[0][0])[i] = 0.f;
    __syncthreads();

    int cnt = min(gcur[b * GRP + g], CAPG);
    const long base = ((long)(b * GRP + g)) * CAPG;
    for (int i = t; i < cnt; i += 256) {
        float2 ab = recAB[base + i];
        uint32_t key = recK[base + i];
        float a = ab.x, bd = ab.y;
        int ca1 = key & 511;
        int wa  = (key >> 9) & 127;
        int cb1 = (key >> 16) & 511;
        int wb  = key >> 25;
        int d = ca1 - r0;
        bool owna = (unsigned)d < (unsigned)rlen;
        int rlo = max(ca1, r0);
        int rhi = min(ca1 + wa, r0 + rlen);
        if (owna) {
            if (cb1 > 0) atomicAdd(&lHG[d][cb1], 1.0f);   // col 0 never read
            for (int ss = cb1; ss < cb1 + wb; ++ss)
                atomicAdd(&lGa[ss * 3 + d], clamp01(bd - lb[ss]));
        }
#pragma unroll
        for (int j = 0; j < GW; ++j) {       // compile-time j -> registers, no scratch
            int r = r0 + j;
            if (r >= rlo && r < rhi) {
                float laj = (j == 0) ? la0 : (j == 1) ? la1 : la2;
                float f = clamp01(a - laj);
                if (cb1 > 0) atomicAdd(&lHG[GW + j][cb1], f);
                for (int ss = cb1; ss < cb1 + wb; ++ss)
                    atomicAdd(&lCsp[j][ss], f * clamp01(bd - lb[ss]));
            }
        }
    }
    __syncthreads();

    // combined suffix-scan of 6 rows along cb1 (9 passes)
    float* src = &lHG[0][0];
    float* dst = &lT[0][0];
    for (int dd = 1; dd < 257; dd <<= 1) {
        for (int i = t; i < 6 * 257; i += 256) {
            int cc = i % 257;
            dst[i] = src[i] + ((cc + dd < 257) ? src[i + dd] : 0.f);
        }
        __syncthreads();
        float* tmp = src; src = dst; dst = tmp;
    }
    int rgb = max(0, min(rlen, NTH - r0));
    for (int rr = 0; rr < rgb; ++rr) {
        const float* gbS = src + (GW + rr) * 257;
        GbC[((long)b * NTH + (r0 + rr)) * NTH + t] = gbS[t + 1] + lCsp[rr][t];
    }
    for (int rr = 0; rr < rlen; ++rr) {
        const float* hS = src + rr * 257;
        float* dsth = H + ((long)b * HD + (r0 + rr)) * HP;
        for (int q = t; q < 257; q += 256)
            dsth[q] = hS[q] + ((q >= 1) ? lGa[(q - 1) * 3 + rr] : 0.f);
    }
}

// column suffix scans along ca1: 4 columns per block, float4 rows (HP pitch -> aligned)
__global__ void __launch_bounds__(256)
k_scanB(float* __restrict__ H) {
    __shared__ float s0[4][264], s1[4][264];
    int b = blockIdx.x / 65, grp = blockIdx.x % 65;
    int c0 = grp * 4;                          // 0..256 (cols 257..259 are pad)
    float* Hb = H + (long)b * HD * HP;
    int t = threadIdx.x;
    for (int row = t; row < HD; row += 256) {
        float4 v = *(const float4*)(Hb + (long)row * HP + c0);
        s0[0][row] = v.x; s0[1][row] = v.y; s0[2][row] = v.z; s0[3][row] = v.w;
    }
    __syncthreads();
    float (*src)[264] = s0, (*dst)[264] = s1;
    int col = t >> 6, lane = t & 63;
    for (int d = 1; d < HD; d <<= 1) {
        for (int i = lane; i < HD; i += 64)
            dst[col][i] = src[col][i] + ((i + d < HD) ? src[col][i + d] : 0.f);
        __syncthreads();
        float (*tmp)[264] = src; src = dst; dst = tmp;
    }
    for (int row = t; row < HD; row += 256) {
        float4 v = make_float4(src[0][row], src[1][row], src[2][row], src[3][row]);
        *(float4*)(Hb + (long)row * HP + c0) = v;
    }
}

// fused assemble + matvec (256 blocks, both s-halves in registers) + last-block finalize
__global__ void __launch_bounds__(256)
k_matvec(const float* __restrict__ H, const float* __restrict__ GbC,
         const float* __restrict__ W,
         const int* __restrict__ ia, const int* __restrict__ ib,
         float* __restrict__ partial, int* __restrict__ mvc,
         const float* __restrict__ bias, float* __restrict__ out) {
    __shared__ float Wl[128][32];
    __shared__ float gl[8][128];
    __shared__ int lastFlag;
    int t = threadIdx.x;
    int r = blockIdx.x;            // 0..255
    int bb = t >> 5, o = t & 31;
    float acc = 0.f;
#pragma unroll
    for (int it = 0; it < 2; ++it) {
        int s0 = it * 128;
        __syncthreads();
        {   // stage 128 gathered W rows (2 threads per row, 64B each)
            int rr = t >> 1, half = t & 1;
            int wrow = ia[r] * 256 + ib[s0 + rr];
            const float4* srcW = reinterpret_cast<const float4*>(W + (long)wrow * 32 + half * 16);
            float4* dstW = reinterpret_cast<float4*>(&Wl[rr][half * 16]);
#pragma unroll
            for (int u = 0; u < 4; ++u) dstW[u] = srcW[u];
        }
        {   // stage assembled glcm chunk for all 8 batches
            int bS = t >> 5, j4 = (t & 31) * 4;
            int sb = s0 + j4;
            const float4 gb = *reinterpret_cast<const float4*>(
                GbC + ((long)bS * NTH + r) * NTH + sb);
            const float* hp = H + ((long)bS * HD + (r + 1)) * HP + 1 + sb;
            float4 v;
            v.x = hp[0] + gb.x;
            v.y = hp[1] + gb.y;
            v.z = hp[2] + gb.z;
            v.w = hp[3] + gb.w;
            *reinterpret_cast<float4*>(&gl[bS][j4]) = v;
        }
        __syncthreads();
#pragma unroll 8
        for (int kk = 0; kk < 128; ++kk) acc += gl[bb][kk] * Wl[kk][o];
    }
    partial[(long)r * 256 + t] = acc;
    __threadfence();
    if (t == 0) lastFlag = (atomicAdd(mvc, 1) == 255) ? 1 : 0;
    __syncthreads();
    if (lastFlag) {
        __threadfence();
        float s = 0.f;
#pragma unroll 16
        for (int c2 = 0; c2 < 256; ++c2) s += partial[(long)c2 * 256 + t];
        out[t] = fmaxf(s + bias[t & 31], 0.f);
    }
}

extern "C" void kernel_launch(void* const* d_in, const int* in_sizes, int n_in,
                              void* d_out, int out_size, void* d_ws, size_t ws_size,
                              hipStream_t stream) {
    const float* x    = (const float*)d_in[0];
    const float* pa   = (const float*)d_in[1];
    const float* pb   = (const float*)d_in[2];
    const float* W    = (const float*)d_in[3];
    const float* bias = (const float*)d_in[4];
    float* out = (float*)d_out;
    float* ws  = (float*)d_ws;

    if (ws_size < (size_t)TOTAL_FLOATS * sizeof(float)) {
        fprintf(stderr, "kernel_launch: ws too small: %zu < %zu bytes\n",
                ws_size, (size_t)TOTAL_FLOATS * sizeof(float));
        return;
    }

    float*    psa   = ws + PSA_OFF;
    int*      ia    = (int*)(ws + IA_OFF);
    float*    psb   = ws + PSB_OFF;
    int*      ib    = (int*)(ws + IB_OFF);
    int*      mvc   = (int*)(ws + MVC_OFF);
    int*      baseA = (int*)(ws + BASEA_OFF);
    int*      baseB = (int*)(ws + BASEB_OFF);
    int*      gcur  = (int*)(ws + GCUR_OFF);
    float*    H     = ws + H_OFF;
    float*    GbC   = ws + GBC_OFF;
    float2*   recAB = (float2*)(ws + RECAB_OFF);
    uint32_t* recK  = (uint32_t*)(ws + RECK_OFF);
    float*    part  = ws + PART_OFF;

    k_sortpub<<<dim3(1), dim3(256), 0, stream>>>(
        pa, pb, psa, ia, psb, ib, baseA, baseB, gcur, mvc);
    k_bin<<<dim3(NCHB, NBATCH), dim3(256), 0, stream>>>(
        x, psa, psb, baseA, baseB, gcur, recAB, recK);
    // phase2 x3: replication probe (idempotent) — Δtotal/2 = phase2 + gap.
    k_phase2<<<dim3(GRP, NBATCH), dim3(256), 0, stream>>>(
        recAB, recK, gcur, psa, psb, H, GbC);
    k_phase2<<<dim3(GRP, NBATCH), dim3(256), 0, stream>>>(
        recAB, recK, gcur, psa, psb, H, GbC);
    k_phase2<<<dim3(GRP, NBATCH), dim3(256), 0, stream>>>(
        recAB, recK, gcur, psa, psb, H, GbC);
    k_scanB<<<dim3(NBATCH * 65), dim3(256), 0, stream>>>(H);
    k_matvec<<<dim3(256), dim3(256), 0, stream>>>(H, GbC, W, ia, ib, part, mvc, bias, out);
}

// Round 12
// 82.634 us; speedup vs baseline: 1.7251x; 1.7251x over previous
//
#include <hip/hip_runtime.h>
#include <cstdio>
#include <cstdint>

static constexpr int  MPIX   = 51529;   // 227*227
static constexpr int  NBATCH = 8;
static constexpr int  NTH    = 256;     // number of thresholds
static constexpr int  HD     = 257;     // rank histogram dim (0..256)
static constexpr int  HP     = 260;     // padded H pitch (rows 16B-aligned)
static constexpr int  GW     = 9;       // rank-group width (R7 geometry)
static constexpr int  GRP    = 29;      // ceil(257/9); 29*8 = 232 blocks, all co-resident
static constexpr int  NCH    = 51;      // pixel chunks of 1024
static constexpr int  CAP    = 128;     // records per (b,g,chunk) cell (post-filter mean ~19)

// ws layout (float slots) — d_ws is 256 MiB
static constexpr long PSA_OFF   = 0;     // 256 floats (sorted phi_a)
static constexpr long IA_OFF    = 256;   // 256 ints
static constexpr long PSB_OFF   = 512;   // 256 floats
static constexpr long IB_OFF    = 768;   // 256 ints
static constexpr long MVC_OFF   = 1024;  // 1 int (matvec ctr; zeroed by k_bin blk(0,0))
static constexpr long CNTC_OFF  = 1056;  // 8*29*51 = 11832 ints (cell counts)
static constexpr long H_OFF     = 12992;
static constexpr long H_SZ      = (long)NBATCH * HD * HP;            // 534560
static constexpr long GBC_OFF   = H_OFF + H_SZ;                      // 547552
static constexpr long GBC_SZ    = (long)NBATCH * NTH * NTH;          // 524288
static constexpr long RECAB_OFF = GBC_OFF + GBC_SZ;                  // 1071840 (even -> float2 ok)
static constexpr long RECAB_SZ  = (long)NBATCH * GRP * NCH * CAP * 2;// 3028992
static constexpr long RECK_OFF  = RECAB_OFF + RECAB_SZ;              // 4100832
static constexpr long RECK_SZ   = (long)NBATCH * GRP * NCH * CAP;    // 1514496
static constexpr long PART_OFF  = RECK_OFF + RECK_SZ;                // 5615328
static constexpr long PART_SZ   = 128 * 256;                         // 32768
static constexpr long TOTAL_FLOATS = PART_OFF + PART_SZ;             // ~22.6 MB

__device__ __forceinline__ float clamp01(float v) {
    return fminf(fmaxf(v, 0.f), 1.f);
}

// LUT decode: c0 = first idx with lv[i] >= v ; c1 = first idx with lv[i] > v-1
__device__ __forceinline__ void decode_lut(const float* __restrict__ lv,
                                           const int* __restrict__ lbase,
                                           float v, int& c1, int& c0) {
    if (v <= 0.f) { c1 = 0; c0 = 0; return; }
    int j = min((int)v, 255);
    int i = lbase[j];
    while (i < 256 && lv[i] < v) ++i;
    c0 = i;
    float u = v - 1.f;
    if (u < 0.f) { c1 = 0; return; }
    int j1 = min((int)u, 255);
    int i1 = lbase[j1];
    while (i1 < 256 && lv[i1] <= u) ++i1;
    c1 = i1;
}

// bin (R7 shape): block (chunk c of 1024 px, batch b), 1024 threads.
// Sorts BOTH threshold sets in-block (cheap, removes a node), builds LUTs, decodes each
// pixel once, FILTERS records with cb1==0 && wb==0 (contribute to no read output),
// writes (a,bd)+key into exclusively-owned (b,g,c) cells. Block (0,0) publishes tables
// for phase2/matvec and zeroes mvc.
__global__ void __launch_bounds__(1024)
k_bin(const float* __restrict__ x, const float* __restrict__ pa, const float* __restrict__ pb,
      int* __restrict__ cntc, float2* __restrict__ recAB, uint32_t* __restrict__ recK,
      float* __restrict__ psa, int* __restrict__ ia,
      float* __restrict__ psb, int* __restrict__ ib, int* __restrict__ mvc) {
    __shared__ float raw[256];
    __shared__ float la[256], lbv[256];
    __shared__ int   lidxA[256], lidxB[256];
    __shared__ int   cnt4[256][4];
    __shared__ int   lbaseA[257], lbaseB[257];
    __shared__ float lx[1025];
    __shared__ int   lcnt[GRP];

    int t = threadIdx.x;
    int c = blockIdx.x, b = blockIdx.y;
    int k0 = c * 1024;

    if (t < 256) raw[t] = pa[t];
    if (t < GRP) lcnt[t] = 0;
    {
        int k = k0 + t;
        lx[t] = (k < MPIX) ? x[(long)b * MPIX + k] : 0.f;
        if (t == 0) lx[1024] = (k0 + 1024 < MPIX) ? x[(long)b * MPIX + k0 + 1024] : 0.f;
    }
    __syncthreads();
    {   // stable rank of phi_a via 4-way split count
        int e = t & 255, q = t >> 8;
        float v = raw[e]; int cc = 0;
        for (int j = q * 64; j < q * 64 + 64; ++j) {
            float w = raw[j];
            cc += (w < v) || (w == v && j < e);
        }
        cnt4[e][q] = cc;
    }
    __syncthreads();
    if (t < 256) {
        int r = cnt4[t][0] + cnt4[t][1] + cnt4[t][2] + cnt4[t][3];
        la[r] = raw[t];
        lidxA[r] = t;
    }
    __syncthreads();
    if (t < 256) raw[t] = pb[t];       // la placement done (barrier above)
    if (t < 257) {                     // LUT A (reads la only)
        float v = (float)t;
        int lo = 0, hi = 256;
        while (lo < hi) { int m = (lo + hi) >> 1; if (la[m] < v) lo = m + 1; else hi = m; }
        lbaseA[t] = lo;
    }
    __syncthreads();
    {   // stable rank of phi_b
        int e = t & 255, q = t >> 8;
        float v = raw[e]; int cc = 0;
        for (int j = q * 64; j < q * 64 + 64; ++j) {
            float w = raw[j];
            cc += (w < v) || (w == v && j < e);
        }
        cnt4[e][q] = cc;
    }
    __syncthreads();
    if (t < 256) {
        int r = cnt4[t][0] + cnt4[t][1] + cnt4[t][2] + cnt4[t][3];
        lbv[r] = raw[t];
        lidxB[r] = t;
    }
    __syncthreads();
    if (t < 257) {                     // LUT B
        float v = (float)t;
        int lo = 0, hi = 256;
        while (lo < hi) { int m = (lo + hi) >> 1; if (lbv[m] < v) lo = m + 1; else hi = m; }
        lbaseB[t] = lo;
    }
    __syncthreads();

    // decode + filter + bin (1 px/thread, segmented cells -> no global atomics)
    {
        int k = k0 + t;
        if (k < MPIX) {
            float a  = lx[t];
            float bd = a - lx[t + 1];
            int ca1, ca0, cb1, cb0;
            decode_lut(la,  lbaseA, a,  ca1, ca0);
            decode_lut(lbv, lbaseB, bd, cb1, cb0);
            int wa = min(ca0 - ca1, 127);
            int wb = min(cb0 - cb1, 127);
            if (cb1 > 0 || wb > 0) {   // FILTER: else contributes to no read output
                uint32_t key = (uint32_t)ca1 | ((uint32_t)wa << 9)
                             | ((uint32_t)cb1 << 16) | ((uint32_t)wb << 25);
                float2 rec = make_float2(a, bd);
                int g0 = ca1 / GW;
                int g1 = min(ca1 + max(wa, 1) - 1, 256) / GW;
                for (int g = g0; g <= g1; ++g) {
                    int slot = atomicAdd(&lcnt[g], 1);
                    if (slot < CAP) {
                        long off = (((long)(b * GRP + g)) * NCH + c) * CAP + slot;
                        recAB[off] = rec;
                        recK[off]  = key;
                    }
                }
            }
        }
    }
    __syncthreads();
    if (t < GRP) cntc[((long)b * GRP + t) * NCH + c] = min(lcnt[t], CAP);

    if (blockIdx.x == 0 && blockIdx.y == 0) {   // block-uniform: publish tables, zero mvc
        if (t < 256) { psa[t] = la[t]; ia[t] = lidxA[t]; psb[t] = lbv[t]; ib[t] = lidxB[t]; }
        if (t == 0) *mvc = 0;
    }
}

// phase2 (R7 shape): block (group g, batch b), 1024 threads, ~58 KB LDS (2 blocks/CU,
// all 232 resident). Wave-shfl cpre; decode-free record loop; combined 18-row suffix
// scan along cb1; flush GbC (finished) and H rows (Ga merged; ca1-scan finishes both).
__global__ void __launch_bounds__(1024)
k_phase2(const float2* __restrict__ recAB, const uint32_t* __restrict__ recK,
         const int* __restrict__ cntc,
         const float* __restrict__ psa, const float* __restrict__ psb,
         float* __restrict__ H, float* __restrict__ GbC) {
    __shared__ float lb[256];
    __shared__ float lla[GW + 1];
    __shared__ float lHG[18][257];   // rows 0..8 = H, rows 9..17 = Gb
    __shared__ float lT[18][257];
    __shared__ float lGa[256][10];   // [s][ca1-r0], padded stride 10
    __shared__ float lCsp[9][256];
    __shared__ int   cpre[NCH + 1];

    int t = threadIdx.x;
    int g = blockIdx.x, b = blockIdx.y;
    int r0 = g * GW;
    int rlen = min(GW, HD - r0);

    if (t < 256) lb[t] = psb[t];
    if (t <= GW) lla[t] = psa[min(r0 + t, 255)];
    for (int i = t; i < 18 * 257; i += 1024) (&lHG[0][0])[i] = 0.f;
    for (int i = t; i < 256 * 10; i += 1024) (&lGa[0][0])[i] = 0.f;
    for (int i = t; i < 9 * 256; i += 1024) (&lCsp[0][0])[i] = 0.f;
    if (t < 64) {   // wave-shfl inclusive prefix of 51 cell counts
        int v = (t < NCH) ? min(cntc[((long)(b * GRP + g)) * NCH + t], CAP) : 0;
        for (int d = 1; d < 64; d <<= 1) {
            int u = __shfl_up(v, d);
            if (t >= d) v += u;
        }
        if (t < NCH) cpre[t + 1] = v;
        if (t == 0) cpre[0] = 0;
    }
    __syncthreads();

    int total = cpre[NCH];
    const float2* abase = recAB + ((long)(b * GRP + g)) * NCH * CAP;
    const uint32_t* kbase = recK + ((long)(b * GRP + g)) * NCH * CAP;
    for (int i = t; i < total; i += 1024) {
        int lo = 0, hi = NCH - 1;   // find c: cpre[c] <= i < cpre[c+1]
        while (lo < hi) { int m = (lo + hi) >> 1; if (cpre[m + 1] <= i) lo = m + 1; else hi = m; }
        int c = lo;
        long off = (long)c * CAP + (i - cpre[c]);
        float2 ab = abase[off];
        uint32_t key = kbase[off];
        float a = ab.x, bd = ab.y;
        int ca1 = key & 511;
        int wa  = (key >> 9) & 127;
        int cb1 = (key >> 16) & 511;
        int wb  = key >> 25;
        int d = ca1 - r0;
        bool owna = (unsigned)d < (unsigned)rlen;
        int rlo = max(ca1, r0);
        int rhi = min(ca1 + wa, r0 + rlen);
        if (owna) {
            if (cb1 > 0) atomicAdd(&lHG[d][cb1], 1.0f);   // col 0 never read
            for (int ss = cb1; ss < cb1 + wb; ++ss)
                atomicAdd(&lGa[ss][d], clamp01(bd - lb[ss]));
        }
        for (int r = rlo; r < rhi; ++r) {
            float f = clamp01(a - lla[r - r0]);
            int rr = r - r0;
            if (cb1 > 0) atomicAdd(&lHG[9 + rr][cb1], f);
            for (int ss = cb1; ss < cb1 + wb; ++ss)
                atomicAdd(&lCsp[rr][ss], f * clamp01(bd - lb[ss]));
        }
    }
    __syncthreads();

    // combined suffix-scan of 18 rows along cb1 (9 passes)
    float* src = &lHG[0][0];
    float* dst = &lT[0][0];
    for (int dd = 1; dd < 257; dd <<= 1) {
        for (int i = t; i < 18 * 257; i += 1024) {
            int cc = i % 257;
            dst[i] = src[i] + ((cc + dd < 257) ? src[i + dd] : 0.f);
        }
        __syncthreads();
        float* tmp = src; src = dst; dst = tmp;
    }
    // flush GbC[r][s] = SufGb[r][s+1] + Csp[r][s]   (fully finished)
    int rgb = max(0, min(rlen, NTH - r0));
    for (int rr = 0; rr < rgb; ++rr) {
        const float* gbS = src + (9 + rr) * 257;
        float* dstg = GbC + ((long)b * NTH + (r0 + rr)) * NTH;
        for (int ss = t; ss < 256; ss += 1024) dstg[ss] = gbS[ss + 1] + lCsp[rr][ss];
    }
    // flush H[p][q] = rowScanH[p][q] + lGa[q-1][p-r0]  (column scan finishes both)
    for (int rr = 0; rr < rlen; ++rr) {
        const float* hS = src + rr * 257;
        float* dsth = H + ((long)b * HD + (r0 + rr)) * HP;
        for (int q = t; q < 257; q += 1024)
            dsth[q] = hS[q] + ((q >= 1) ? lGa[q - 1][rr] : 0.f);
    }
}

// column suffix scans along ca1: 4 columns per block, float4 rows (HP pitch -> aligned)
__global__ void __launch_bounds__(256)
k_scanB(float* __restrict__ H) {
    __shared__ float s0[4][264], s1[4][264];
    int b = blockIdx.x / 65, grp = blockIdx.x % 65;
    int c0 = grp * 4;                          // 0..256 (cols 257..259 are pad)
    float* Hb = H + (long)b * HD * HP;
    int t = threadIdx.x;
    for (int row = t; row < HD; row += 256) {
        float4 v = *(const float4*)(Hb + (long)row * HP + c0);
        s0[0][row] = v.x; s0[1][row] = v.y; s0[2][row] = v.z; s0[3][row] = v.w;
    }
    __syncthreads();
    float (*src)[264] = s0, (*dst)[264] = s1;
    int col = t >> 6, lane = t & 63;
    for (int d = 1; d < HD; d <<= 1) {
        for (int i = lane; i < HD; i += 64)
            dst[col][i] = src[col][i] + ((i + d < HD) ? src[col][i + d] : 0.f);
        __syncthreads();
        float (*tmp)[264] = src; src = dst; dst = tmp;
    }
    for (int row = t; row < HD; row += 256) {
        float4 v = make_float4(src[0][row], src[1][row], src[2][row], src[3][row]);
        *(float4*)(Hb + (long)row * HP + c0) = v;
    }
}

// fused assemble + matvec (R7 shape: 128 blocks x 4 chunks) + last-block finalize
__global__ void __launch_bounds__(256)
k_matvec(const float* __restrict__ H, const float* __restrict__ GbC,
         const float* __restrict__ W,
         const int* __restrict__ ia, const int* __restrict__ ib,
         float* __restrict__ partial, int* __restrict__ mvc,
         const float* __restrict__ bias, float* __restrict__ out) {
    __shared__ float Wl[128][32];
    __shared__ float gl[8][128];
    __shared__ int lastFlag;
    int t = threadIdx.x;
    int bb = t >> 5, o = t & 31;
    float acc = 0.f;
#pragma unroll
    for (int it = 0; it < 4; ++it) {
        int r  = blockIdx.x * 2 + (it >> 1);   // 0..255
        int s0 = (it & 1) * 128;
        __syncthreads();   // protect previous round's LDS reads
        {   // stage 128 gathered W rows (2 threads per row, 64B each)
            int rr = t >> 1, half = t & 1;
            int wrow = ia[r] * 256 + ib[s0 + rr];
            const float4* srcW = reinterpret_cast<const float4*>(W + (long)wrow * 32 + half * 16);
            float4* dstW = reinterpret_cast<float4*>(&Wl[rr][half * 16]);
#pragma unroll
            for (int u = 0; u < 4; ++u) dstW[u] = srcW[u];
        }
        {   // stage assembled glcm chunk for all 8 batches
            int bS = t >> 5, j4 = (t & 31) * 4;
            int sb = s0 + j4;
            const float4 gb = *reinterpret_cast<const float4*>(
                GbC + ((long)bS * NTH + r) * NTH + sb);
            const float* hp = H + ((long)bS * HD + (r + 1)) * HP + 1 + sb;
            float4 v;
            v.x = hp[0] + gb.x;
            v.y = hp[1] + gb.y;
            v.z = hp[2] + gb.z;
            v.w = hp[3] + gb.w;
            *reinterpret_cast<float4*>(&gl[bS][j4]) = v;
        }
        __syncthreads();
#pragma unroll 8
        for (int kk = 0; kk < 128; ++kk) acc += gl[bb][kk] * Wl[kk][o];
    }
    partial[(long)blockIdx.x * 256 + t] = acc;
    __threadfence();
    if (t == 0) lastFlag = (atomicAdd(mvc, 1) == 127) ? 1 : 0;
    __syncthreads();
    if (lastFlag) {
        __threadfence();
        float s = 0.f;
#pragma unroll 16
        for (int c2 = 0; c2 < 128; ++c2) s += partial[(long)c2 * 256 + t];
        out[t] = fmaxf(s + bias[t & 31], 0.f);
    }
}

extern "C" void kernel_launch(void* const* d_in, const int* in_sizes, int n_in,
                              void* d_out, int out_size, void* d_ws, size_t ws_size,
                              hipStream_t stream) {
    const float* x    = (const float*)d_in[0];
    const float* pa   = (const float*)d_in[1];
    const float* pb   = (const float*)d_in[2];
    const float* W    = (const float*)d_in[3];
    const float* bias = (const float*)d_in[4];
    float* out = (float*)d_out;
    float* ws  = (float*)d_ws;

    if (ws_size < (size_t)TOTAL_FLOATS * sizeof(float)) {
        fprintf(stderr, "kernel_launch: ws too small: %zu < %zu bytes\n",
                ws_size, (size_t)TOTAL_FLOATS * sizeof(float));
        return;
    }

    float*    psa   = ws + PSA_OFF;
    int*      ia    = (int*)(ws + IA_OFF);
    float*    psb   = ws + PSB_OFF;
    int*      ib    = (int*)(ws + IB_OFF);
    int*      mvc   = (int*)(ws + MVC_OFF);
    int*      cntc  = (int*)(ws + CNTC_OFF);
    float*    H     = ws + H_OFF;
    float*    GbC   = ws + GBC_OFF;
    float2*   recAB = (float2*)(ws + RECAB_OFF);
    uint32_t* recK  = (uint32_t*)(ws + RECK_OFF);
    float*    part  = ws + PART_OFF;

    k_bin<<<dim3(NCH, NBATCH), dim3(1024), 0, stream>>>(
        x, pa, pb, cntc, recAB, recK, psa, ia, psb, ib, mvc);
    k_phase2<<<dim3(GRP, NBATCH), dim3(1024), 0, stream>>>(
        recAB, recK, cntc, psa, psb, H, GbC);
    k_scanB<<<dim3(NBATCH * 65), dim3(256), 0, stream>>>(H);
    k_matvec<<<dim3(128), dim3(256), 0, stream>>>(H, GbC, W, ia, ib, part, mvc, bias, out);
}